// Round 17
// baseline (841.945 us; speedup 1.0000x reference)
//
#include <hip/hip_runtime.h>
#include <hip/hip_bf16.h>

// Round 17: revert FF1 to 128²-tile gemm_kernel (gemm256's 1-block/CU grid
// exposed every barrier drain — regime-gate violation; r16 regressed 812->834).
// Keep r15/16's epilogue fusions (OUTMODE 3 residual, OUTMODE 4 E_time).

#define TSEQ 1024
#define BB   8
#define CDIM 512
#define HH   8
#define KHD  64
#define FFD  2048
#define LL   6
#define MROWS (BB*TSEQ)   // 8192

typedef __hip_bfloat16 bf16;
typedef __attribute__((ext_vector_type(8))) short bf16x8;
typedef __attribute__((ext_vector_type(4))) short bf16x4;
typedef __attribute__((ext_vector_type(4))) float f32x4;

#define MFMA16K16(a,b,c) __builtin_amdgcn_mfma_f32_16x16x16bf16_1k(a,b,c,0,0,0)

static __device__ __forceinline__ short f2bf_bits(float x) {
    bf16 t = __float2bfloat16(x);
    return *reinterpret_cast<short*>(&t);
}
static __device__ __forceinline__ float bf2f(short b) {
    unsigned u = ((unsigned)(unsigned short)b) << 16;
    return __uint_as_float(u);
}

static __device__ __forceinline__ void gload_lds16(const bf16* g, short* l) {
    __builtin_amdgcn_global_load_lds(
        (__attribute__((address_space(1))) const void*)g,
        (__attribute__((address_space(3))) void*)l, 16, 0, 0);
}

// ---------------------------------------------------------------------------
// Weight prep (r12 version).
// ---------------------------------------------------------------------------
struct PrepJob { const float* src; long dstOff; int nrows; int kd; int type; };
struct PrepArgs { PrepJob jobs[48]; };

__global__ void __launch_bounds__(256) prep_weights(PrepArgs args, bf16* __restrict__ wsb)
{
    PrepJob J = args.jobs[blockIdx.y];
    const int tilesK = (J.kd + 63) >> 6;
    const int tilesN = (J.nrows + 63) >> 6;
    const int t = blockIdx.x;
    if (t >= tilesK * tilesN) return;
    const int tn = t / tilesK, tk = t - tn * tilesK;
    const int n0 = tn << 6, k0 = tk << 6;

    __shared__ float tile[64][65];
    const int tid = threadIdx.x;
    const bool full = (J.type != 3) && (n0 + 64 <= J.nrows) && (k0 + 64 <= J.kd);

    if (full) {
        const int c4 = (tid & 15) * 4;
        const int r0 = tid >> 4;
#pragma unroll
        for (int i = 0; i < 4; ++i) {
            int kl = r0 + i * 16;
            int k = k0 + kl;
            const float* src;
            if (J.type == 0) src = J.src + (long)k * J.nrows + n0 + c4;
            else             src = J.src + ((long)(n0 >> 6) * J.kd + k) * 64 + c4;
            float4 v = *(const float4*)src;
            tile[kl][c4 + 0] = v.x; tile[kl][c4 + 1] = v.y;
            tile[kl][c4 + 2] = v.z; tile[kl][c4 + 3] = v.w;
        }
        __syncthreads();
        const int kq = (tid & 15) * 4;
        const int n1 = tid >> 4;
#pragma unroll
        for (int i = 0; i < 4; ++i) {
            int nl = n1 + i * 16;
            bf16x4 o;
#pragma unroll
            for (int j2 = 0; j2 < 4; ++j2) o[j2] = f2bf_bits(tile[kq + j2][nl]);
            *(bf16x4*)(wsb + J.dstOff + (long)(n0 + nl) * J.kd + k0 + kq) = o;
        }
    } else {
#pragma unroll
        for (int i = 0; i < 16; ++i) {
            int e = tid + i * 256;
            int kl = e >> 6, nl = e & 63;
            int k = k0 + kl, n = n0 + nl;
            float v = 0.f;
            if (J.type != 3 && k < J.kd && n < J.nrows) {
                if (J.type == 0) v = J.src[(long)k * J.nrows + n];
                else             v = J.src[((long)(n >> 6) * J.kd + k) * 64 + (n & 63)];
            }
            tile[kl][nl] = v;
        }
        __syncthreads();
#pragma unroll
        for (int i = 0; i < 16; ++i) {
            int e = tid + i * 256;
            int nl = e >> 6, kl = e & 63;
            int n = n0 + nl, k = k0 + kl;
            if (n < J.nrows && k < J.kd)
                wsb[J.dstOff + (long)n * J.kd + k] = __float2bfloat16(tile[kl][nl]);
        }
    }
}

__global__ void build_head_bias(const float* __restrict__ b_oh, const float* __restrict__ b_rh,
                                const float* __restrict__ b_dh, float* __restrict__ hb)
{
    int i = threadIdx.x;
    float v = 0.f;
    if (i < 128) v = b_oh[i];
    else if (i < 169) v = b_rh[i - 128];
    else if (i == 169) v = b_dh[0];
    hb[i] = v;
}

// ---------------------------------------------------------------------------
// Generic bf16 GEMM, 128xTN tile (2-phase + XOR swizzle).
// OUTMODE: 0=f32, 1=bf16, 2=head scatter, 3=+res(bf16)->bf16,
//          4=+E_time[step[row]]->bf16.
// ---------------------------------------------------------------------------
template<int TN, int BK, int OUTMODE, bool BIAS, bool RELU>
__global__ void __launch_bounds__(256) gemm_kernel(
    const bf16* __restrict__ A, const bf16* __restrict__ BT,
    void* __restrict__ Cout, const float* __restrict__ bias,
    int M, int N, int Kd,
    const void* __restrict__ aux1, const float* __restrict__ aux2)
{
    constexpr int NJ = TN / 32;
    constexpr int SL = BK / 8;
    constexpr int AI = (128 * BK) / (8 * 256);
    constexpr int BI = (TN  * BK) / (8 * 256);
    __shared__ short As[128 * BK];
    __shared__ short Bs[TN * BK];
    const int tid = threadIdx.x;
    const int lane = tid & 63;
    const int w = tid >> 6;
    const int wm = w >> 1, wn = w & 1;
    const int m0 = blockIdx.x * 128;
    const int n0 = blockIdx.y * TN;
    const int g = lane >> 4, lr = lane & 15;

    f32x4 acc[4][NJ] = {};

    for (int k0 = 0; k0 < Kd; k0 += BK) {
#pragma unroll
        for (int it = 0; it < AI; ++it) {
            int cbase = (w * AI + it) * 64;
            int c = cbase + lane;
            int row = c / SL, slot = c % SL;
            int ss = slot ^ (row & (SL - 1));
            gload_lds16(A + (size_t)(m0 + row) * Kd + k0 + ss * 8, As + cbase * 8);
        }
#pragma unroll
        for (int it = 0; it < BI; ++it) {
            int cbase = (w * BI + it) * 64;
            int c = cbase + lane;
            int row = c / SL, slot = c % SL;
            int ss = slot ^ (row & (SL - 1));
            gload_lds16(BT + (size_t)(n0 + row) * Kd + k0 + ss * 8, Bs + cbase * 8);
        }
        __syncthreads();
#pragma unroll
        for (int kk = 0; kk < BK; kk += 32) {
            bf16x8 af[4], bfr[NJ];
#pragma unroll
            for (int i = 0; i < 4; ++i) {
                int row = wm*64 + i*16 + lr;
                int ss = ((kk >> 3) + g) ^ (row & (SL - 1));
                af[i] = *(const bf16x8*)(As + row * BK + ss * 8);
            }
#pragma unroll
            for (int j = 0; j < NJ; ++j) {
                int row = wn*(TN/2) + j*16 + lr;
                int ss = ((kk >> 3) + g) ^ (row & (SL - 1));
                bfr[j] = *(const bf16x8*)(Bs + row * BK + ss * 8);
            }
#pragma unroll
            for (int i = 0; i < 4; ++i)
#pragma unroll
                for (int j = 0; j < NJ; ++j)
                    acc[i][j] = __builtin_amdgcn_mfma_f32_16x16x32_bf16(af[i], bfr[j], acc[i][j], 0, 0, 0);
        }
        __syncthreads();
    }

#pragma unroll
    for (int i = 0; i < 4; ++i) {
#pragma unroll
        for (int j = 0; j < NJ; ++j) {
            int col = n0 + wn*(TN/2) + j*16 + lr;
            float bv = 0.f;
            if (BIAS) bv = bias[col];
#pragma unroll
            for (int r = 0; r < 4; ++r) {
                int row = m0 + wm*64 + i*16 + g*4 + r;
                float v = acc[i][j][r] + bv;
                if (RELU) v = fmaxf(v, 0.f);
                if (OUTMODE == 1) {
                    ((bf16*)Cout)[(size_t)row * N + col] = __float2bfloat16(v);
                } else if (OUTMODE == 2) {
                    float* outf = (float*)Cout;
                    if (col < 128)      outf[(size_t)row * 128 + col] = v;
                    else if (col < 169) outf[1048576 + (size_t)row * 41 + (col - 128)] = v;
                    else if (col == 169) outf[1384448 + (size_t)row] = v;
                } else if (OUTMODE == 3) {
                    const bf16* res = (const bf16*)aux1;
                    v += bf2f(*(const short*)(res + (size_t)row * N + col));
                    ((bf16*)Cout)[(size_t)row * N + col] = __float2bfloat16(v);
                } else if (OUTMODE == 4) {
                    const int* stp = (const int*)aux1;
                    v += aux2[(size_t)stp[row] * 512 + col];
                    ((bf16*)Cout)[(size_t)row * N + col] = __float2bfloat16(v);
                } else {
                    ((float*)Cout)[(size_t)row * N + col] = v;
                }
            }
        }
    }
}

// ---------------------------------------------------------------------------
// Flash attention (unchanged from r13/r14).
// ---------------------------------------------------------------------------
__global__ void __launch_bounds__(256) attn_kernel(const bf16* __restrict__ qkv, bf16* __restrict__ o)
{
    const int bh = blockIdx.x;
    const int z  = blockIdx.y;
    const int b = bh >> 3, h = bh & 7;
    const int tid = threadIdx.x, lane = tid & 63, w = tid >> 6;
    const int g = lane >> 4, lr = lane & 15;
    const int qlo = z, qhi = 15 - z;
    const float SCL = 0.125f * 1.44269504089f;

    __shared__ short Ks[128][72];
    __shared__ short Vs[8192];

    const size_t base = (size_t)b * TSEQ * 1536;

    bf16x8 qfL[2], qfH[2];
#pragma unroll
    for (int kk = 0; kk < 2; ++kk) {
        qfL[kk] = *(const bf16x8*)(qkv + base + (size_t)(qlo*64 + w*16 + lr) * 1536 + h*64 + kk*32 + g*8);
        qfH[kk] = *(const bf16x8*)(qkv + base + (size_t)(qhi*64 + w*16 + lr) * 1536 + h*64 + kk*32 + g*8);
    }

    f32x4 accL[4] = {}, accH[4] = {};
    float mL = -1e30f, lL = 0.f, mH = -1e30f, lH = 0.f;

    const short* vtr = &Vs[lane * 4];

    auto proc = [&](const bf16x8* qf, f32x4* acc, float& m, float& l, int qt, int kt) {
        f32x4 st[8];
        __builtin_amdgcn_s_setprio(1);
#pragma unroll
        for (int j = 0; j < 8; ++j) {
            st[j] = f32x4{0.f, 0.f, 0.f, 0.f};
#pragma unroll
            for (int kk = 0; kk < 2; ++kk) {
                bf16x8 af = *(const bf16x8*)(&Ks[j*16 + lr][kk*32 + g*8]);
                st[j] = __builtin_amdgcn_mfma_f32_16x16x32_bf16(af, qf[kk], st[j], 0, 0, 0);
            }
        }
        __builtin_amdgcn_s_setprio(0);
        const int qg = qt*64 + w*16 + lr;
        const bool diag = (kt == (qt >> 1));
        float vmax = -1e30f;
#pragma unroll
        for (int j = 0; j < 8; ++j)
#pragma unroll
            for (int r = 0; r < 4; ++r) {
                float v = st[j][r] * SCL;
                if (diag && (kt*128 + j*16 + g*4 + r) > qg) v = -1e30f;
                st[j][r] = v;
                vmax = fmaxf(vmax, v);
            }
        vmax = fmaxf(vmax, __shfl_xor(vmax, 16));
        vmax = fmaxf(vmax, __shfl_xor(vmax, 32));
        if (!__all(vmax <= m + 8.f)) {
            float mn = fmaxf(m, vmax);
            float alpha = exp2f(m - mn);
            l *= alpha;
            float av[4];
#pragma unroll
            for (int r = 0; r < 4; ++r) av[r] = __shfl(alpha, g*4 + r);
#pragma unroll
            for (int dj = 0; dj < 4; ++dj)
#pragma unroll
                for (int r = 0; r < 4; ++r) acc[dj][r] *= av[r];
            m = mn;
        }
        float psum = 0.f;
        bf16x4 pf[8];
#pragma unroll
        for (int j = 0; j < 8; ++j)
#pragma unroll
            for (int r = 0; r < 4; ++r) {
                float p = exp2f(st[j][r] - m);
                psum += p;
                pf[j][r] = f2bf_bits(p);
            }
        psum += __shfl_xor(psum, 16);
        psum += __shfl_xor(psum, 32);
        l += psum;
#pragma unroll
        for (int half = 0; half < 4; ++half) {
            bf16x4 vf[2][4];
#pragma unroll
            for (int jj = 0; jj < 2; ++jj)
#pragma unroll
                for (int dj = 0; dj < 4; ++dj) {
                    asm volatile("ds_read_b64_tr_b16 %0, %1"
                        : "=v"(vf[jj][dj])
                        : "v"((const __attribute__((address_space(3))) short*)
                              (vtr + ((half*2 + jj)*4 + dj) * 256)));
                }
            asm volatile("s_waitcnt lgkmcnt(0)" ::: "memory");
            __builtin_amdgcn_sched_barrier(0);
            __builtin_amdgcn_s_setprio(1);
#pragma unroll
            for (int jj = 0; jj < 2; ++jj)
#pragma unroll
                for (int dj = 0; dj < 4; ++dj)
                    acc[dj] = MFMA16K16(pf[half*2 + jj], vf[jj][dj], acc[dj]);
            __builtin_amdgcn_s_setprio(0);
        }
    };

    const int ktmax = qhi >> 1;
    for (int kt = 0; kt <= ktmax; ++kt) {
#pragma unroll
        for (int it = 0; it < 4; ++it) {
            int idx = tid + it * 256;
            int row = idx >> 3;
            int col = (idx & 7) << 3;
            *(bf16x8*)(&Ks[row][col]) =
                *(const bf16x8*)(qkv + base + (size_t)(kt*128 + row)*1536 + 512 + h*64 + col);
            bf16x8 vv = *(const bf16x8*)(qkv + base + (size_t)(kt*128 + row)*1536 + 1024 + h*64 + col);
            int dst = ((row >> 4)*4 + (col >> 4))*256 + (row & 15)*16 + (col & 8);
            *(bf16x8*)(&Vs[dst]) = vv;
        }
        __syncthreads();
        proc(qfH, accH, mH, lH, qhi, kt);
        if (kt <= (qlo >> 1)) proc(qfL, accL, mL, lL, qlo, kt);
        __syncthreads();
    }

    auto wout = [&](const f32x4* acc, float l, int qt) {
        float linv = 1.f / l;
        float lv[4];
#pragma unroll
        for (int r = 0; r < 4; ++r) lv[r] = __shfl(linv, g*4 + r);
#pragma unroll
        for (int dj = 0; dj < 4; ++dj)
#pragma unroll
            for (int r = 0; r < 4; ++r) {
                int trow = qt*64 + w*16 + g*4 + r;
                o[((size_t)(b*TSEQ + trow))*512 + h*64 + dj*16 + lr] =
                    __float2bfloat16(acc[dj][r] * lv[r]);
            }
    };
    wout(accH, lH, qhi);
    wout(accL, lL, qlo);
}

// ---------------------------------------------------------------------------
// LayerNorm over a single bf16 stream u; writes bf16 xb.
// ---------------------------------------------------------------------------
__global__ void __launch_bounds__(256) ln_kernel(
    const bf16* __restrict__ u_, bf16* __restrict__ xb,
    const float* __restrict__ gamma, const float* __restrict__ beta)
{
    int row = blockIdx.x * 4 + (threadIdx.x >> 6);
    int lane = threadIdx.x & 63;
    int c0 = lane * 8;
    size_t rb = (size_t)row * CDIM + c0;
    float u[8];
    bf16x8 yv = *(const bf16x8*)(u_ + rb);
#pragma unroll
    for (int i = 0; i < 8; ++i) u[i] = bf2f(yv[i]);
    float s = 0.f, sq = 0.f;
#pragma unroll
    for (int i = 0; i < 8; ++i) { s += u[i]; sq += u[i]*u[i]; }
#pragma unroll
    for (int off = 1; off < 64; off <<= 1) { s += __shfl_xor(s, off); sq += __shfl_xor(sq, off); }
    float mean = s * (1.f / 512.f);
    float var  = sq * (1.f / 512.f) - mean * mean;
    float rstd = rsqrtf(var + 1e-5f);
    float4 g0 = *(const float4*)(gamma + c0);
    float4 g1 = *(const float4*)(gamma + c0 + 4);
    float4 be0 = *(const float4*)(beta + c0);
    float4 be1v = *(const float4*)(beta + c0 + 4);
    float gv[8] = {g0.x,g0.y,g0.z,g0.w,g1.x,g1.y,g1.z,g1.w};
    float bv[8] = {be0.x,be0.y,be0.z,be0.w,be1v.x,be1v.y,be1v.z,be1v.w};
    bf16x8 ob;
#pragma unroll
    for (int i = 0; i < 8; ++i)
        ob[i] = f2bf_bits((u[i] - mean) * rstd * gv[i] + bv[i]);
    *(bf16x8*)(xb + rb) = ob;
}

// ---------------------------------------------------------------------------
// Embedding glue
// ---------------------------------------------------------------------------
__global__ void __launch_bounds__(256) obs_convert(const float* __restrict__ obs, bf16* __restrict__ out)
{
    int idx = (blockIdx.x * 256 + threadIdx.x) * 4;
    float4 v = *(const float4*)(obs + idx);
    bf16x4 o = { f2bf_bits(v.x), f2bf_bits(v.y), f2bf_bits(v.z), f2bf_bits(v.w) };
    *(bf16x4*)(out + idx) = o;
}

__global__ void __launch_bounds__(256) concat_kernel(
    const bf16* __restrict__ obs_emb, const int* __restrict__ action,
    const float* __restrict__ E_act, bf16* __restrict__ cc)
{
    int row = blockIdx.x;
    int a = action[row];
    int c = threadIdx.x * 4;
    if (c < 512) {
        *(bf16x4*)(cc + (size_t)row * 1024 + c) =
            *(const bf16x4*)(obs_emb + (size_t)row * 512 + c);
    } else {
        float4 v = *(const float4*)(E_act + (size_t)a * 512 + (c - 512));
        bf16x4 o = { f2bf_bits(v.x), f2bf_bits(v.y), f2bf_bits(v.z), f2bf_bits(v.w) };
        *(bf16x4*)(cc + (size_t)row * 1024 + c) = o;
    }
}

// ---------------------------------------------------------------------------
extern "C" void kernel_launch(void* const* d_in, const int* in_sizes, int n_in,
                              void* d_out, int out_size, void* d_ws, size_t ws_size,
                              hipStream_t stream)
{
    const float* obs    = (const float*)d_in[0];
    const int*   action = (const int*)  d_in[1];
    const int*   step   = (const int*)  d_in[2];
    const float* W_obs  = (const float*)d_in[3];
    const float* b_obs  = (const float*)d_in[4];
    const float* E_act  = (const float*)d_in[5];
    const float* W_traj = (const float*)d_in[6];
    const float* b_traj = (const float*)d_in[7];
    const float* E_time = (const float*)d_in[8];
    const float* Wq  = (const float*)d_in[9];
    const float* Wk  = (const float*)d_in[10];
    const float* Wv  = (const float*)d_in[11];
    const float* Wp  = (const float*)d_in[12];
    const float* bp  = (const float*)d_in[13];
    const float* W1  = (const float*)d_in[14];
    const float* b1  = (const float*)d_in[15];
    const float* W2  = (const float*)d_in[16];
    const float* b2  = (const float*)d_in[17];
    const float* g1  = (const float*)d_in[18];
    const float* be1 = (const float*)d_in[19];
    const float* g2  = (const float*)d_in[20];
    const float* be2 = (const float*)d_in[21];
    const float* gf  = (const float*)d_in[22];
    const float* bfp = (const float*)d_in[23];
    const float* W_oh = (const float*)d_in[24];
    const float* b_oh = (const float*)d_in[25];
    const float* W_rh = (const float*)d_in[26];
    const float* b_rh = (const float*)d_in[27];
    const float* W_dh = (const float*)d_in[28];
    const float* b_dh = (const float*)d_in[29];

    char* ws  = (char*)d_ws;
    bf16* wsb = (bf16*)ws;

    long off = 0;
    const long oWT_obs  = off; off += 512L * 128;
    const long oWT_traj = off; off += 512L * 1024;
    const long oWT_qkv  = off; off += 6L * 1536 * 512;
    const long oWT_p    = off; off += 6L * 512 * 512;
    const long oWT_1    = off; off += 6L * 2048 * 512;
    const long oWT_2    = off; off += 6L * 512 * 2048;
    const long oWT_hd   = off; off += 256L * 512;
    size_t byteOff = ((size_t)off * 2 + 255) & ~(size_t)255;

    auto take = [&](size_t bytes) {
        void* p = ws + byteOff;
        byteOff = (byteOff + bytes + 255) & ~(size_t)255;
        return p;
    };
    float* head_bias = (float*)take(256 * 4);
    bf16*  xb   = (bf16*) take((size_t)MROWS * 512 * 2);
    bf16*  qkv  = (bf16*) take((size_t)MROWS * 1536 * 2);
    bf16*  o    = (bf16*) take((size_t)MROWS * 512 * 2);
    bf16*  hbuf = (bf16*) take((size_t)MROWS * 2048 * 2);
    (void)ws_size; (void)in_sizes; (void)n_in; (void)out_size;

    PrepArgs pa;
    int nj = 0;
    auto addJob = [&](const float* src, long dstOff, int nrows, int kd, int type) {
        pa.jobs[nj].src = src; pa.jobs[nj].dstOff = dstOff;
        pa.jobs[nj].nrows = nrows; pa.jobs[nj].kd = kd; pa.jobs[nj].type = type; ++nj;
    };
    addJob(W_obs,  oWT_obs,  512, 128,  0);
    addJob(W_traj, oWT_traj, 512, 1024, 0);
    for (int l = 0; l < 6; ++l) {
        long qb = oWT_qkv + (long)l * 1536 * 512;
        addJob(Wq + (long)l * 8 * 512 * 64, qb,               512, 512, 1);
        addJob(Wk + (long)l * 8 * 512 * 64, qb + 512L * 512,  512, 512, 1);
        addJob(Wv + (long)l * 8 * 512 * 64, qb + 1024L * 512, 512, 512, 1);
        addJob(Wp + (long)l * 512 * 512,  oWT_p + (long)l * 512 * 512,  512,  512,  0);
        addJob(W1 + (long)l * 512 * 2048, oWT_1 + (long)l * 2048 * 512, 2048, 512,  0);
        addJob(W2 + (long)l * 2048 * 512, oWT_2 + (long)l * 512 * 2048, 512,  2048, 0);
    }
    addJob(W_oh, oWT_hd,             128, 512, 0);
    addJob(W_rh, oWT_hd + 128L*512,  41,  512, 0);
    addJob(W_dh, oWT_hd + 169L*512,  1,   512, 0);
    addJob(nullptr, oWT_hd + 170L*512, 86, 512, 3);

    prep_weights<<<dim3(256, nj), 256, 0, stream>>>(pa, wsb);
    build_head_bias<<<1, 256, 0, stream>>>(b_oh, b_rh, b_dh, head_bias);

    // ---- embedding ----
    bf16* obs_bf = o;
    obs_convert<<<(MROWS * 128) / 1024, 256, 0, stream>>>(obs, obs_bf);
    bf16* obs_emb = qkv;
    gemm_kernel<64, 128, 1, true, false><<<dim3(64, 8), 256, 0, stream>>>(
        obs_bf, wsb + oWT_obs, obs_emb, b_obs, MROWS, 512, 128, nullptr, nullptr);
    bf16* cc = hbuf;
    concat_kernel<<<MROWS, 256, 0, stream>>>(obs_emb, action, E_act, cc);
    // traj GEMM + E_time[step] fused -> xb
    gemm_kernel<64, 128, 4, true, false><<<dim3(64, 8), 256, 0, stream>>>(
        cc, wsb + oWT_traj, xb, b_traj, MROWS, 512, 1024, step, E_time);

    // ---- layers ----
    for (int l = 0; l < 6; ++l) {
        gemm_kernel<128, 64, 1, false, false><<<dim3(64, 12), 256, 0, stream>>>(
            xb, wsb + oWT_qkv + (long)l * 1536 * 512, qkv, nullptr, MROWS, 1536, 512, nullptr, nullptr);
        attn_kernel<<<dim3(64, 8), 256, 0, stream>>>(qkv, o);
        // proj + residual(xb) -> u1 (into qkv area, 512-stride)
        bf16* u1 = qkv;
        gemm_kernel<64, 128, 3, true, false><<<dim3(64, 8), 256, 0, stream>>>(
            o, wsb + oWT_p + (long)l * 512 * 512, u1, bp + (long)l * 512, MROWS, 512, 512, xb, nullptr);
        ln_kernel<<<MROWS / 4, 256, 0, stream>>>(u1, xb, g1 + l * 512, be1 + l * 512);
        gemm_kernel<128, 64, 1, true, true><<<dim3(64, 16), 256, 0, stream>>>(
            xb, wsb + oWT_1 + (long)l * 2048 * 512, hbuf, b1 + l * 2048, MROWS, 2048, 512, nullptr, nullptr);
        // FF2 + residual(xb) -> o
        gemm_kernel<64, 128, 3, true, false><<<dim3(64, 8), 256, 0, stream>>>(
            hbuf, wsb + oWT_2 + (long)l * 512 * 2048, o, b2 + l * 512, MROWS, 512, 2048, xb, nullptr);
        ln_kernel<<<MROWS / 4, 256, 0, stream>>>(o, xb, g2 + l * 512, be2 + l * 512);
    }

    // ---- final norm (in-place on xb) + heads ----
    ln_kernel<<<MROWS / 4, 256, 0, stream>>>(xb, xb, gf, bfp);
    gemm_kernel<64, 128, 2, true, false><<<dim3(64, 4), 256, 0, stream>>>(
        xb, wsb + oWT_hd, d_out, head_bias, MROWS, 256, 512, nullptr, nullptr);
}

// Round 18
// 815.258 us; speedup vs baseline: 1.0327x; 1.0327x over previous
//
#include <hip/hip_runtime.h>
#include <hip/hip_bf16.h>

// Round 18: revert to r14 structure (two-input LN; proj/FF2 OUTMODE 1 — the
// OUTMODE-3 residual fusion's scalar epilogue reads regressed r16/r17), keep
// ONLY the OUTMODE-4 traj+E_time fusion (deletes xinit kernel outright).

#define TSEQ 1024
#define BB   8
#define CDIM 512
#define HH   8
#define KHD  64
#define FFD  2048
#define LL   6
#define MROWS (BB*TSEQ)   // 8192

typedef __hip_bfloat16 bf16;
typedef __attribute__((ext_vector_type(8))) short bf16x8;
typedef __attribute__((ext_vector_type(4))) short bf16x4;
typedef __attribute__((ext_vector_type(4))) float f32x4;

#define MFMA16K16(a,b,c) __builtin_amdgcn_mfma_f32_16x16x16bf16_1k(a,b,c,0,0,0)

static __device__ __forceinline__ short f2bf_bits(float x) {
    bf16 t = __float2bfloat16(x);
    return *reinterpret_cast<short*>(&t);
}
static __device__ __forceinline__ float bf2f(short b) {
    unsigned u = ((unsigned)(unsigned short)b) << 16;
    return __uint_as_float(u);
}

static __device__ __forceinline__ void gload_lds16(const bf16* g, short* l) {
    __builtin_amdgcn_global_load_lds(
        (__attribute__((address_space(1))) const void*)g,
        (__attribute__((address_space(3))) void*)l, 16, 0, 0);
}

// ---------------------------------------------------------------------------
// Weight prep (r12 version).
// ---------------------------------------------------------------------------
struct PrepJob { const float* src; long dstOff; int nrows; int kd; int type; };
struct PrepArgs { PrepJob jobs[48]; };

__global__ void __launch_bounds__(256) prep_weights(PrepArgs args, bf16* __restrict__ wsb)
{
    PrepJob J = args.jobs[blockIdx.y];
    const int tilesK = (J.kd + 63) >> 6;
    const int tilesN = (J.nrows + 63) >> 6;
    const int t = blockIdx.x;
    if (t >= tilesK * tilesN) return;
    const int tn = t / tilesK, tk = t - tn * tilesK;
    const int n0 = tn << 6, k0 = tk << 6;

    __shared__ float tile[64][65];
    const int tid = threadIdx.x;
    const bool full = (J.type != 3) && (n0 + 64 <= J.nrows) && (k0 + 64 <= J.kd);

    if (full) {
        const int c4 = (tid & 15) * 4;
        const int r0 = tid >> 4;
#pragma unroll
        for (int i = 0; i < 4; ++i) {
            int kl = r0 + i * 16;
            int k = k0 + kl;
            const float* src;
            if (J.type == 0) src = J.src + (long)k * J.nrows + n0 + c4;
            else             src = J.src + ((long)(n0 >> 6) * J.kd + k) * 64 + c4;
            float4 v = *(const float4*)src;
            tile[kl][c4 + 0] = v.x; tile[kl][c4 + 1] = v.y;
            tile[kl][c4 + 2] = v.z; tile[kl][c4 + 3] = v.w;
        }
        __syncthreads();
        const int kq = (tid & 15) * 4;
        const int n1 = tid >> 4;
#pragma unroll
        for (int i = 0; i < 4; ++i) {
            int nl = n1 + i * 16;
            bf16x4 o;
#pragma unroll
            for (int j2 = 0; j2 < 4; ++j2) o[j2] = f2bf_bits(tile[kq + j2][nl]);
            *(bf16x4*)(wsb + J.dstOff + (long)(n0 + nl) * J.kd + k0 + kq) = o;
        }
    } else {
#pragma unroll
        for (int i = 0; i < 16; ++i) {
            int e = tid + i * 256;
            int kl = e >> 6, nl = e & 63;
            int k = k0 + kl, n = n0 + nl;
            float v = 0.f;
            if (J.type != 3 && k < J.kd && n < J.nrows) {
                if (J.type == 0) v = J.src[(long)k * J.nrows + n];
                else             v = J.src[((long)(n >> 6) * J.kd + k) * 64 + (n & 63)];
            }
            tile[kl][nl] = v;
        }
        __syncthreads();
#pragma unroll
        for (int i = 0; i < 16; ++i) {
            int e = tid + i * 256;
            int nl = e >> 6, kl = e & 63;
            int n = n0 + nl, k = k0 + kl;
            if (n < J.nrows && k < J.kd)
                wsb[J.dstOff + (long)n * J.kd + k] = __float2bfloat16(tile[kl][nl]);
        }
    }
}

__global__ void build_head_bias(const float* __restrict__ b_oh, const float* __restrict__ b_rh,
                                const float* __restrict__ b_dh, float* __restrict__ hb)
{
    int i = threadIdx.x;
    float v = 0.f;
    if (i < 128) v = b_oh[i];
    else if (i < 169) v = b_rh[i - 128];
    else if (i == 169) v = b_dh[0];
    hb[i] = v;
}

// ---------------------------------------------------------------------------
// Generic bf16 GEMM, 128xTN tile (2-phase + XOR swizzle).
// OUTMODE: 0=f32, 1=bf16, 2=head scatter, 4=+E_time[step[row]]->bf16.
// ---------------------------------------------------------------------------
template<int TN, int BK, int OUTMODE, bool BIAS, bool RELU>
__global__ void __launch_bounds__(256) gemm_kernel(
    const bf16* __restrict__ A, const bf16* __restrict__ BT,
    void* __restrict__ Cout, const float* __restrict__ bias,
    int M, int N, int Kd,
    const void* __restrict__ aux1, const float* __restrict__ aux2)
{
    constexpr int NJ = TN / 32;
    constexpr int SL = BK / 8;
    constexpr int AI = (128 * BK) / (8 * 256);
    constexpr int BI = (TN  * BK) / (8 * 256);
    __shared__ short As[128 * BK];
    __shared__ short Bs[TN * BK];
    const int tid = threadIdx.x;
    const int lane = tid & 63;
    const int w = tid >> 6;
    const int wm = w >> 1, wn = w & 1;
    const int m0 = blockIdx.x * 128;
    const int n0 = blockIdx.y * TN;
    const int g = lane >> 4, lr = lane & 15;

    f32x4 acc[4][NJ] = {};

    for (int k0 = 0; k0 < Kd; k0 += BK) {
#pragma unroll
        for (int it = 0; it < AI; ++it) {
            int cbase = (w * AI + it) * 64;
            int c = cbase + lane;
            int row = c / SL, slot = c % SL;
            int ss = slot ^ (row & (SL - 1));
            gload_lds16(A + (size_t)(m0 + row) * Kd + k0 + ss * 8, As + cbase * 8);
        }
#pragma unroll
        for (int it = 0; it < BI; ++it) {
            int cbase = (w * BI + it) * 64;
            int c = cbase + lane;
            int row = c / SL, slot = c % SL;
            int ss = slot ^ (row & (SL - 1));
            gload_lds16(BT + (size_t)(n0 + row) * Kd + k0 + ss * 8, Bs + cbase * 8);
        }
        __syncthreads();
#pragma unroll
        for (int kk = 0; kk < BK; kk += 32) {
            bf16x8 af[4], bfr[NJ];
#pragma unroll
            for (int i = 0; i < 4; ++i) {
                int row = wm*64 + i*16 + lr;
                int ss = ((kk >> 3) + g) ^ (row & (SL - 1));
                af[i] = *(const bf16x8*)(As + row * BK + ss * 8);
            }
#pragma unroll
            for (int j = 0; j < NJ; ++j) {
                int row = wn*(TN/2) + j*16 + lr;
                int ss = ((kk >> 3) + g) ^ (row & (SL - 1));
                bfr[j] = *(const bf16x8*)(Bs + row * BK + ss * 8);
            }
#pragma unroll
            for (int i = 0; i < 4; ++i)
#pragma unroll
                for (int j = 0; j < NJ; ++j)
                    acc[i][j] = __builtin_amdgcn_mfma_f32_16x16x32_bf16(af[i], bfr[j], acc[i][j], 0, 0, 0);
        }
        __syncthreads();
    }

#pragma unroll
    for (int i = 0; i < 4; ++i) {
#pragma unroll
        for (int j = 0; j < NJ; ++j) {
            int col = n0 + wn*(TN/2) + j*16 + lr;
            float bv = 0.f;
            if (BIAS) bv = bias[col];
#pragma unroll
            for (int r = 0; r < 4; ++r) {
                int row = m0 + wm*64 + i*16 + g*4 + r;
                float v = acc[i][j][r] + bv;
                if (RELU) v = fmaxf(v, 0.f);
                if (OUTMODE == 1) {
                    ((bf16*)Cout)[(size_t)row * N + col] = __float2bfloat16(v);
                } else if (OUTMODE == 2) {
                    float* outf = (float*)Cout;
                    if (col < 128)      outf[(size_t)row * 128 + col] = v;
                    else if (col < 169) outf[1048576 + (size_t)row * 41 + (col - 128)] = v;
                    else if (col == 169) outf[1384448 + (size_t)row] = v;
                } else if (OUTMODE == 4) {
                    const int* stp = (const int*)aux1;
                    v += aux2[(size_t)stp[row] * 512 + col];
                    ((bf16*)Cout)[(size_t)row * N + col] = __float2bfloat16(v);
                } else {
                    ((float*)Cout)[(size_t)row * N + col] = v;
                }
            }
        }
    }
}

// ---------------------------------------------------------------------------
// Flash attention (unchanged from r13/r14).
// ---------------------------------------------------------------------------
__global__ void __launch_bounds__(256) attn_kernel(const bf16* __restrict__ qkv, bf16* __restrict__ o)
{
    const int bh = blockIdx.x;
    const int z  = blockIdx.y;
    const int b = bh >> 3, h = bh & 7;
    const int tid = threadIdx.x, lane = tid & 63, w = tid >> 6;
    const int g = lane >> 4, lr = lane & 15;
    const int qlo = z, qhi = 15 - z;
    const float SCL = 0.125f * 1.44269504089f;

    __shared__ short Ks[128][72];
    __shared__ short Vs[8192];

    const size_t base = (size_t)b * TSEQ * 1536;

    bf16x8 qfL[2], qfH[2];
#pragma unroll
    for (int kk = 0; kk < 2; ++kk) {
        qfL[kk] = *(const bf16x8*)(qkv + base + (size_t)(qlo*64 + w*16 + lr) * 1536 + h*64 + kk*32 + g*8);
        qfH[kk] = *(const bf16x8*)(qkv + base + (size_t)(qhi*64 + w*16 + lr) * 1536 + h*64 + kk*32 + g*8);
    }

    f32x4 accL[4] = {}, accH[4] = {};
    float mL = -1e30f, lL = 0.f, mH = -1e30f, lH = 0.f;

    const short* vtr = &Vs[lane * 4];

    auto proc = [&](const bf16x8* qf, f32x4* acc, float& m, float& l, int qt, int kt) {
        f32x4 st[8];
        __builtin_amdgcn_s_setprio(1);
#pragma unroll
        for (int j = 0; j < 8; ++j) {
            st[j] = f32x4{0.f, 0.f, 0.f, 0.f};
#pragma unroll
            for (int kk = 0; kk < 2; ++kk) {
                bf16x8 af = *(const bf16x8*)(&Ks[j*16 + lr][kk*32 + g*8]);
                st[j] = __builtin_amdgcn_mfma_f32_16x16x32_bf16(af, qf[kk], st[j], 0, 0, 0);
            }
        }
        __builtin_amdgcn_s_setprio(0);
        const int qg = qt*64 + w*16 + lr;
        const bool diag = (kt == (qt >> 1));
        float vmax = -1e30f;
#pragma unroll
        for (int j = 0; j < 8; ++j)
#pragma unroll
            for (int r = 0; r < 4; ++r) {
                float v = st[j][r] * SCL;
                if (diag && (kt*128 + j*16 + g*4 + r) > qg) v = -1e30f;
                st[j][r] = v;
                vmax = fmaxf(vmax, v);
            }
        vmax = fmaxf(vmax, __shfl_xor(vmax, 16));
        vmax = fmaxf(vmax, __shfl_xor(vmax, 32));
        if (!__all(vmax <= m + 8.f)) {
            float mn = fmaxf(m, vmax);
            float alpha = exp2f(m - mn);
            l *= alpha;
            float av[4];
#pragma unroll
            for (int r = 0; r < 4; ++r) av[r] = __shfl(alpha, g*4 + r);
#pragma unroll
            for (int dj = 0; dj < 4; ++dj)
#pragma unroll
                for (int r = 0; r < 4; ++r) acc[dj][r] *= av[r];
            m = mn;
        }
        float psum = 0.f;
        bf16x4 pf[8];
#pragma unroll
        for (int j = 0; j < 8; ++j)
#pragma unroll
            for (int r = 0; r < 4; ++r) {
                float p = exp2f(st[j][r] - m);
                psum += p;
                pf[j][r] = f2bf_bits(p);
            }
        psum += __shfl_xor(psum, 16);
        psum += __shfl_xor(psum, 32);
        l += psum;
#pragma unroll
        for (int half = 0; half < 4; ++half) {
            bf16x4 vf[2][4];
#pragma unroll
            for (int jj = 0; jj < 2; ++jj)
#pragma unroll
                for (int dj = 0; dj < 4; ++dj) {
                    asm volatile("ds_read_b64_tr_b16 %0, %1"
                        : "=v"(vf[jj][dj])
                        : "v"((const __attribute__((address_space(3))) short*)
                              (vtr + ((half*2 + jj)*4 + dj) * 256)));
                }
            asm volatile("s_waitcnt lgkmcnt(0)" ::: "memory");
            __builtin_amdgcn_sched_barrier(0);
            __builtin_amdgcn_s_setprio(1);
#pragma unroll
            for (int jj = 0; jj < 2; ++jj)
#pragma unroll
                for (int dj = 0; dj < 4; ++dj)
                    acc[dj] = MFMA16K16(pf[half*2 + jj], vf[jj][dj], acc[dj]);
            __builtin_amdgcn_s_setprio(0);
        }
    };

    const int ktmax = qhi >> 1;
    for (int kt = 0; kt <= ktmax; ++kt) {
#pragma unroll
        for (int it = 0; it < 4; ++it) {
            int idx = tid + it * 256;
            int row = idx >> 3;
            int col = (idx & 7) << 3;
            *(bf16x8*)(&Ks[row][col]) =
                *(const bf16x8*)(qkv + base + (size_t)(kt*128 + row)*1536 + 512 + h*64 + col);
            bf16x8 vv = *(const bf16x8*)(qkv + base + (size_t)(kt*128 + row)*1536 + 1024 + h*64 + col);
            int dst = ((row >> 4)*4 + (col >> 4))*256 + (row & 15)*16 + (col & 8);
            *(bf16x8*)(&Vs[dst]) = vv;
        }
        __syncthreads();
        proc(qfH, accH, mH, lH, qhi, kt);
        if (kt <= (qlo >> 1)) proc(qfL, accL, mL, lL, qlo, kt);
        __syncthreads();
    }

    auto wout = [&](const f32x4* acc, float l, int qt) {
        float linv = 1.f / l;
        float lv[4];
#pragma unroll
        for (int r = 0; r < 4; ++r) lv[r] = __shfl(linv, g*4 + r);
#pragma unroll
        for (int dj = 0; dj < 4; ++dj)
#pragma unroll
            for (int r = 0; r < 4; ++r) {
                int trow = qt*64 + w*16 + g*4 + r;
                o[((size_t)(b*TSEQ + trow))*512 + h*64 + dj*16 + lr] =
                    __float2bfloat16(acc[dj][r] * lv[r]);
            }
    };
    wout(accH, lH, qhi);
    wout(accL, lL, qlo);
}

// ---------------------------------------------------------------------------
// Fused residual + LayerNorm (r14 version): u = y + xin (both bf16, f32
// math); out -> xb (bf16).  In-place xb safe (row-local).
// ---------------------------------------------------------------------------
template<bool HAS_RES>
__global__ void __launch_bounds__(256) ln_kernel(
    const bf16* __restrict__ y_, const bf16* __restrict__ xin,
    bf16* __restrict__ xb,
    const float* __restrict__ gamma, const float* __restrict__ beta)
{
    int row = blockIdx.x * 4 + (threadIdx.x >> 6);
    int lane = threadIdx.x & 63;
    int c0 = lane * 8;
    size_t rb = (size_t)row * CDIM + c0;
    float u[8];
    bf16x8 yv = *(const bf16x8*)(y_ + rb);
#pragma unroll
    for (int i = 0; i < 8; ++i) u[i] = bf2f(yv[i]);
    if (HAS_RES) {
        bf16x8 xv = *(const bf16x8*)(xin + rb);
#pragma unroll
        for (int i = 0; i < 8; ++i) u[i] += bf2f(xv[i]);
    }
    float s = 0.f, sq = 0.f;
#pragma unroll
    for (int i = 0; i < 8; ++i) { s += u[i]; sq += u[i]*u[i]; }
#pragma unroll
    for (int off = 1; off < 64; off <<= 1) { s += __shfl_xor(s, off); sq += __shfl_xor(sq, off); }
    float mean = s * (1.f / 512.f);
    float var  = sq * (1.f / 512.f) - mean * mean;
    float rstd = rsqrtf(var + 1e-5f);
    float4 g0 = *(const float4*)(gamma + c0);
    float4 g1 = *(const float4*)(gamma + c0 + 4);
    float4 be0 = *(const float4*)(beta + c0);
    float4 be1v = *(const float4*)(beta + c0 + 4);
    float gv[8] = {g0.x,g0.y,g0.z,g0.w,g1.x,g1.y,g1.z,g1.w};
    float bv[8] = {be0.x,be0.y,be0.z,be0.w,be1v.x,be1v.y,be1v.z,be1v.w};
    bf16x8 ob;
#pragma unroll
    for (int i = 0; i < 8; ++i)
        ob[i] = f2bf_bits((u[i] - mean) * rstd * gv[i] + bv[i]);
    *(bf16x8*)(xb + rb) = ob;
}

// ---------------------------------------------------------------------------
// Embedding glue
// ---------------------------------------------------------------------------
__global__ void __launch_bounds__(256) obs_convert(const float* __restrict__ obs, bf16* __restrict__ out)
{
    int idx = (blockIdx.x * 256 + threadIdx.x) * 4;
    float4 v = *(const float4*)(obs + idx);
    bf16x4 o = { f2bf_bits(v.x), f2bf_bits(v.y), f2bf_bits(v.z), f2bf_bits(v.w) };
    *(bf16x4*)(out + idx) = o;
}

__global__ void __launch_bounds__(256) concat_kernel(
    const bf16* __restrict__ obs_emb, const int* __restrict__ action,
    const float* __restrict__ E_act, bf16* __restrict__ cc)
{
    int row = blockIdx.x;
    int a = action[row];
    int c = threadIdx.x * 4;
    if (c < 512) {
        *(bf16x4*)(cc + (size_t)row * 1024 + c) =
            *(const bf16x4*)(obs_emb + (size_t)row * 512 + c);
    } else {
        float4 v = *(const float4*)(E_act + (size_t)a * 512 + (c - 512));
        bf16x4 o = { f2bf_bits(v.x), f2bf_bits(v.y), f2bf_bits(v.z), f2bf_bits(v.w) };
        *(bf16x4*)(cc + (size_t)row * 1024 + c) = o;
    }
}

// ---------------------------------------------------------------------------
extern "C" void kernel_launch(void* const* d_in, const int* in_sizes, int n_in,
                              void* d_out, int out_size, void* d_ws, size_t ws_size,
                              hipStream_t stream)
{
    const float* obs    = (const float*)d_in[0];
    const int*   action = (const int*)  d_in[1];
    const int*   step   = (const int*)  d_in[2];
    const float* W_obs  = (const float*)d_in[3];
    const float* b_obs  = (const float*)d_in[4];
    const float* E_act  = (const float*)d_in[5];
    const float* W_traj = (const float*)d_in[6];
    const float* b_traj = (const float*)d_in[7];
    const float* E_time = (const float*)d_in[8];
    const float* Wq  = (const float*)d_in[9];
    const float* Wk  = (const float*)d_in[10];
    const float* Wv  = (const float*)d_in[11];
    const float* Wp  = (const float*)d_in[12];
    const float* bp  = (const float*)d_in[13];
    const float* W1  = (const float*)d_in[14];
    const float* b1  = (const float*)d_in[15];
    const float* W2  = (const float*)d_in[16];
    const float* b2  = (const float*)d_in[17];
    const float* g1  = (const float*)d_in[18];
    const float* be1 = (const float*)d_in[19];
    const float* g2  = (const float*)d_in[20];
    const float* be2 = (const float*)d_in[21];
    const float* gf  = (const float*)d_in[22];
    const float* bfp = (const float*)d_in[23];
    const float* W_oh = (const float*)d_in[24];
    const float* b_oh = (const float*)d_in[25];
    const float* W_rh = (const float*)d_in[26];
    const float* b_rh = (const float*)d_in[27];
    const float* W_dh = (const float*)d_in[28];
    const float* b_dh = (const float*)d_in[29];

    char* ws  = (char*)d_ws;
    bf16* wsb = (bf16*)ws;

    long off = 0;
    const long oWT_obs  = off; off += 512L * 128;
    const long oWT_traj = off; off += 512L * 1024;
    const long oWT_qkv  = off; off += 6L * 1536 * 512;
    const long oWT_p    = off; off += 6L * 512 * 512;
    const long oWT_1    = off; off += 6L * 2048 * 512;
    const long oWT_2    = off; off += 6L * 512 * 2048;
    const long oWT_hd   = off; off += 256L * 512;
    size_t byteOff = ((size_t)off * 2 + 255) & ~(size_t)255;

    auto take = [&](size_t bytes) {
        void* p = ws + byteOff;
        byteOff = (byteOff + bytes + 255) & ~(size_t)255;
        return p;
    };
    float* head_bias = (float*)take(256 * 4);
    bf16*  xb   = (bf16*) take((size_t)MROWS * 512 * 2);
    bf16*  qkv  = (bf16*) take((size_t)MROWS * 1536 * 2);
    bf16*  o    = (bf16*) take((size_t)MROWS * 512 * 2);
    bf16*  hbuf = (bf16*) take((size_t)MROWS * 2048 * 2);
    (void)ws_size; (void)in_sizes; (void)n_in; (void)out_size;

    PrepArgs pa;
    int nj = 0;
    auto addJob = [&](const float* src, long dstOff, int nrows, int kd, int type) {
        pa.jobs[nj].src = src; pa.jobs[nj].dstOff = dstOff;
        pa.jobs[nj].nrows = nrows; pa.jobs[nj].kd = kd; pa.jobs[nj].type = type; ++nj;
    };
    addJob(W_obs,  oWT_obs,  512, 128,  0);
    addJob(W_traj, oWT_traj, 512, 1024, 0);
    for (int l = 0; l < 6; ++l) {
        long qb = oWT_qkv + (long)l * 1536 * 512;
        addJob(Wq + (long)l * 8 * 512 * 64, qb,               512, 512, 1);
        addJob(Wk + (long)l * 8 * 512 * 64, qb + 512L * 512,  512, 512, 1);
        addJob(Wv + (long)l * 8 * 512 * 64, qb + 1024L * 512, 512, 512, 1);
        addJob(Wp + (long)l * 512 * 512,  oWT_p + (long)l * 512 * 512,  512,  512,  0);
        addJob(W1 + (long)l * 512 * 2048, oWT_1 + (long)l * 2048 * 512, 2048, 512,  0);
        addJob(W2 + (long)l * 2048 * 512, oWT_2 + (long)l * 512 * 2048, 512,  2048, 0);
    }
    addJob(W_oh, oWT_hd,             128, 512, 0);
    addJob(W_rh, oWT_hd + 128L*512,  41,  512, 0);
    addJob(W_dh, oWT_hd + 169L*512,  1,   512, 0);
    addJob(nullptr, oWT_hd + 170L*512, 86, 512, 3);

    prep_weights<<<dim3(256, nj), 256, 0, stream>>>(pa, wsb);
    build_head_bias<<<1, 256, 0, stream>>>(b_oh, b_rh, b_dh, head_bias);

    // ---- embedding ----
    bf16* obs_bf = o;
    obs_convert<<<(MROWS * 128) / 1024, 256, 0, stream>>>(obs, obs_bf);
    bf16* obs_emb = qkv;
    gemm_kernel<64, 128, 1, true, false><<<dim3(64, 8), 256, 0, stream>>>(
        obs_bf, wsb + oWT_obs, obs_emb, b_obs, MROWS, 512, 128, nullptr, nullptr);
    bf16* cc = hbuf;
    concat_kernel<<<MROWS, 256, 0, stream>>>(obs_emb, action, E_act, cc);
    // traj GEMM + E_time[step] fused -> xb  (kept from r15: deletes xinit)
    gemm_kernel<64, 128, 4, true, false><<<dim3(64, 8), 256, 0, stream>>>(
        cc, wsb + oWT_traj, xb, b_traj, MROWS, 512, 1024, step, E_time);

    // ---- layers (r14 structure) ----
    for (int l = 0; l < 6; ++l) {
        gemm_kernel<128, 64, 1, false, false><<<dim3(64, 12), 256, 0, stream>>>(
            xb, wsb + oWT_qkv + (long)l * 1536 * 512, qkv, nullptr, MROWS, 1536, 512, nullptr, nullptr);
        attn_kernel<<<dim3(64, 8), 256, 0, stream>>>(qkv, o);
        gemm_kernel<64, 128, 1, true, false><<<dim3(64, 8), 256, 0, stream>>>(
            o, wsb + oWT_p + (long)l * 512 * 512, hbuf, bp + (long)l * 512, MROWS, 512, 512, nullptr, nullptr);
        ln_kernel<true><<<MROWS / 4, 256, 0, stream>>>(
            hbuf, xb, xb, g1 + l * 512, be1 + l * 512);
        gemm_kernel<128, 64, 1, true, true><<<dim3(64, 16), 256, 0, stream>>>(
            xb, wsb + oWT_1 + (long)l * 2048 * 512, hbuf, b1 + l * 2048, MROWS, 2048, 512, nullptr, nullptr);
        gemm_kernel<64, 128, 1, true, false><<<dim3(64, 8), 256, 0, stream>>>(
            hbuf, wsb + oWT_2 + (long)l * 512 * 2048, o, b2 + l * 512, MROWS, 512, 2048, nullptr, nullptr);
        ln_kernel<true><<<MROWS / 4, 256, 0, stream>>>(
            o, xb, xb, g2 + l * 512, be2 + l * 512);
    }

    // ---- final norm (in-place on xb) + heads ----
    ln_kernel<false><<<MROWS / 4, 256, 0, stream>>>(
        xb, nullptr, xb, gf, bfp);
    gemm_kernel<64, 128, 2, true, false><<<dim3(64, 4), 256, 0, stream>>>(
        xb, wsb + oWT_hd, d_out, head_bias, MROWS, 256, 512, nullptr, nullptr);
}

// Round 21
// 803.038 us; speedup vs baseline: 1.0485x; 1.0152x over previous
//
#include <hip/hip_runtime.h>
#include <hip/hip_bf16.h>

// Round 21: identical to rounds 19/20 — both were infra failures
// (UnresponsiveContainer); the 8-phase FF1 experiment has not yet run.
// 8-phase counted-vmcnt 256x256 GEMM for FF1 (stage stream S[P+6],
// vmcnt(8)->4->0, superrow-pair swizzle); rest = r18.

#define TSEQ 1024
#define BB   8
#define CDIM 512
#define HH   8
#define KHD  64
#define FFD  2048
#define LL   6
#define MROWS (BB*TSEQ)   // 8192

typedef __hip_bfloat16 bf16;
typedef __attribute__((ext_vector_type(8))) short bf16x8;
typedef __attribute__((ext_vector_type(4))) short bf16x4;
typedef __attribute__((ext_vector_type(4))) float f32x4;

#define MFMA16K16(a,b,c) __builtin_amdgcn_mfma_f32_16x16x16bf16_1k(a,b,c,0,0,0)

static __device__ __forceinline__ short f2bf_bits(float x) {
    bf16 t = __float2bfloat16(x);
    return *reinterpret_cast<short*>(&t);
}
static __device__ __forceinline__ float bf2f(short b) {
    unsigned u = ((unsigned)(unsigned short)b) << 16;
    return __uint_as_float(u);
}

static __device__ __forceinline__ void gload_lds16(const bf16* g, short* l) {
    __builtin_amdgcn_global_load_lds(
        (__attribute__((address_space(1))) const void*)g,
        (__attribute__((address_space(3))) void*)l, 16, 0, 0);
}

// ---------------------------------------------------------------------------
// Weight prep (r12 version).
// ---------------------------------------------------------------------------
struct PrepJob { const float* src; long dstOff; int nrows; int kd; int type; };
struct PrepArgs { PrepJob jobs[48]; };

__global__ void __launch_bounds__(256) prep_weights(PrepArgs args, bf16* __restrict__ wsb)
{
    PrepJob J = args.jobs[blockIdx.y];
    const int tilesK = (J.kd + 63) >> 6;
    const int tilesN = (J.nrows + 63) >> 6;
    const int t = blockIdx.x;
    if (t >= tilesK * tilesN) return;
    const int tn = t / tilesK, tk = t - tn * tilesK;
    const int n0 = tn << 6, k0 = tk << 6;

    __shared__ float tile[64][65];
    const int tid = threadIdx.x;
    const bool full = (J.type != 3) && (n0 + 64 <= J.nrows) && (k0 + 64 <= J.kd);

    if (full) {
        const int c4 = (tid & 15) * 4;
        const int r0 = tid >> 4;
#pragma unroll
        for (int i = 0; i < 4; ++i) {
            int kl = r0 + i * 16;
            int k = k0 + kl;
            const float* src;
            if (J.type == 0) src = J.src + (long)k * J.nrows + n0 + c4;
            else             src = J.src + ((long)(n0 >> 6) * J.kd + k) * 64 + c4;
            float4 v = *(const float4*)src;
            tile[kl][c4 + 0] = v.x; tile[kl][c4 + 1] = v.y;
            tile[kl][c4 + 2] = v.z; tile[kl][c4 + 3] = v.w;
        }
        __syncthreads();
        const int kq = (tid & 15) * 4;
        const int n1 = tid >> 4;
#pragma unroll
        for (int i = 0; i < 4; ++i) {
            int nl = n1 + i * 16;
            bf16x4 o;
#pragma unroll
            for (int j2 = 0; j2 < 4; ++j2) o[j2] = f2bf_bits(tile[kq + j2][nl]);
            *(bf16x4*)(wsb + J.dstOff + (long)(n0 + nl) * J.kd + k0 + kq) = o;
        }
    } else {
#pragma unroll
        for (int i = 0; i < 16; ++i) {
            int e = tid + i * 256;
            int kl = e >> 6, nl = e & 63;
            int k = k0 + kl, n = n0 + nl;
            float v = 0.f;
            if (J.type != 3 && k < J.kd && n < J.nrows) {
                if (J.type == 0) v = J.src[(long)k * J.nrows + n];
                else             v = J.src[((long)(n >> 6) * J.kd + k) * 64 + (n & 63)];
            }
            tile[kl][nl] = v;
        }
        __syncthreads();
#pragma unroll
        for (int i = 0; i < 16; ++i) {
            int e = tid + i * 256;
            int nl = e >> 6, kl = e & 63;
            int n = n0 + nl, k = k0 + kl;
            if (n < J.nrows && k < J.kd)
                wsb[J.dstOff + (long)n * J.kd + k] = __float2bfloat16(tile[kl][nl]);
        }
    }
}

__global__ void build_head_bias(const float* __restrict__ b_oh, const float* __restrict__ b_rh,
                                const float* __restrict__ b_dh, float* __restrict__ hb)
{
    int i = threadIdx.x;
    float v = 0.f;
    if (i < 128) v = b_oh[i];
    else if (i < 169) v = b_rh[i - 128];
    else if (i == 169) v = b_dh[0];
    hb[i] = v;
}

// ---------------------------------------------------------------------------
// Generic bf16 GEMM, 128xTN (2-phase + XOR swizzle).  OUTMODE: 0=f32,
// 1=bf16, 2=head scatter, 4=+E_time[step[row]]->bf16.
// ---------------------------------------------------------------------------
template<int TN, int BK, int OUTMODE, bool BIAS, bool RELU>
__global__ void __launch_bounds__(256) gemm_kernel(
    const bf16* __restrict__ A, const bf16* __restrict__ BT,
    void* __restrict__ Cout, const float* __restrict__ bias,
    int M, int N, int Kd,
    const void* __restrict__ aux1, const float* __restrict__ aux2)
{
    constexpr int NJ = TN / 32;
    constexpr int SL = BK / 8;
    constexpr int AI = (128 * BK) / (8 * 256);
    constexpr int BI = (TN  * BK) / (8 * 256);
    __shared__ short As[128 * BK];
    __shared__ short Bs[TN * BK];
    const int tid = threadIdx.x;
    const int lane = tid & 63;
    const int w = tid >> 6;
    const int wm = w >> 1, wn = w & 1;
    const int m0 = blockIdx.x * 128;
    const int n0 = blockIdx.y * TN;
    const int g = lane >> 4, lr = lane & 15;

    f32x4 acc[4][NJ] = {};

    for (int k0 = 0; k0 < Kd; k0 += BK) {
#pragma unroll
        for (int it = 0; it < AI; ++it) {
            int cbase = (w * AI + it) * 64;
            int c = cbase + lane;
            int row = c / SL, slot = c % SL;
            int ss = slot ^ (row & (SL - 1));
            gload_lds16(A + (size_t)(m0 + row) * Kd + k0 + ss * 8, As + cbase * 8);
        }
#pragma unroll
        for (int it = 0; it < BI; ++it) {
            int cbase = (w * BI + it) * 64;
            int c = cbase + lane;
            int row = c / SL, slot = c % SL;
            int ss = slot ^ (row & (SL - 1));
            gload_lds16(BT + (size_t)(n0 + row) * Kd + k0 + ss * 8, Bs + cbase * 8);
        }
        __syncthreads();
#pragma unroll
        for (int kk = 0; kk < BK; kk += 32) {
            bf16x8 af[4], bfr[NJ];
#pragma unroll
            for (int i = 0; i < 4; ++i) {
                int row = wm*64 + i*16 + lr;
                int ss = ((kk >> 3) + g) ^ (row & (SL - 1));
                af[i] = *(const bf16x8*)(As + row * BK + ss * 8);
            }
#pragma unroll
            for (int j = 0; j < NJ; ++j) {
                int row = wn*(TN/2) + j*16 + lr;
                int ss = ((kk >> 3) + g) ^ (row & (SL - 1));
                bfr[j] = *(const bf16x8*)(Bs + row * BK + ss * 8);
            }
#pragma unroll
            for (int i = 0; i < 4; ++i)
#pragma unroll
                for (int j = 0; j < NJ; ++j)
                    acc[i][j] = __builtin_amdgcn_mfma_f32_16x16x32_bf16(af[i], bfr[j], acc[i][j], 0, 0, 0);
        }
        __syncthreads();
    }

#pragma unroll
    for (int i = 0; i < 4; ++i) {
#pragma unroll
        for (int j = 0; j < NJ; ++j) {
            int col = n0 + wn*(TN/2) + j*16 + lr;
            float bv = 0.f;
            if (BIAS) bv = bias[col];
#pragma unroll
            for (int r = 0; r < 4; ++r) {
                int row = m0 + wm*64 + i*16 + g*4 + r;
                float v = acc[i][j][r] + bv;
                if (RELU) v = fmaxf(v, 0.f);
                if (OUTMODE == 1) {
                    ((bf16*)Cout)[(size_t)row * N + col] = __float2bfloat16(v);
                } else if (OUTMODE == 2) {
                    float* outf = (float*)Cout;
                    if (col < 128)      outf[(size_t)row * 128 + col] = v;
                    else if (col < 169) outf[1048576 + (size_t)row * 41 + (col - 128)] = v;
                    else if (col == 169) outf[1384448 + (size_t)row] = v;
                } else if (OUTMODE == 4) {
                    const int* stp = (const int*)aux1;
                    v += aux2[(size_t)stp[row] * 512 + col];
                    ((bf16*)Cout)[(size_t)row * N + col] = __float2bfloat16(v);
                } else {
                    ((float*)Cout)[(size_t)row * N + col] = v;
                }
            }
        }
    }
}

// ---------------------------------------------------------------------------
// 8-phase 256x256 GEMM (FF1).  512 thr = 8 waves (2M x 4N); per-wave C =
// 128x64 (8x4 frags).  K-tiles of 64 split into kh halves of 32.  LDS:
// [2 dbuf][2 kh] x (256 rows x 32 shorts) for A and B = 128 KB.
// Superrow-pair swizzle: chunk c -> sr=c>>3, u=(c&7)^(sr&7),
// row=sr*2+(u>>2), klocal=(u&3)*8; reads apply the same involution.
// Stage stream S = [A.k0,B.k0,A.k1,B.k1] per tile; stage(P)=S[P+6];
// prologue S[0..5]+vmcnt(8); tail vmcnt at odd phases (8,...,8,4,0).
// Phase: {8 ds_read; stage; [vmcnt]; bar; setprio 16 MFMA; bar}.
// ---------------------------------------------------------------------------
template<bool BIAS, bool RELU>
__global__ void __launch_bounds__(512, 1) gemm8p_kernel(
    const bf16* __restrict__ A, const bf16* __restrict__ BT,
    bf16* __restrict__ Cout, const float* __restrict__ bias,
    int M, int N, int Kd)
{
    __shared__ short Ab[2][2][8192];   // 64 KB
    __shared__ short Bb[2][2][8192];   // 64 KB
    const int tid = threadIdx.x, lane = tid & 63, w = tid >> 6;
    const int wr = w >> 2, wc = w & 3;
    const int m0 = blockIdx.x * 256, n0 = blockIdx.y * 256;
    const int g = lane >> 4, lr = lane & 15;

    const int nt = Kd / 64;
    const int NS = nt * 4;

    auto stage = [&](int s) {
        const int ts = s >> 2, kind = s & 3;
        const int kh = kind >> 1, buf = ts & 1;
        const bf16* src = (kind & 1) ? BT : A;
        const int base0 = (kind & 1) ? n0 : m0;
        short* dst = (kind & 1) ? Bb[buf][kh] : Ab[buf][kh];
        const int k0t = ts * 64 + kh * 32;
#pragma unroll
        for (int it = 0; it < 2; ++it) {
            int cbase = it * 512 + w * 64;
            int c = cbase + lane;
            int sr = c >> 3;
            int u = (c & 7) ^ (sr & 7);
            int row = sr * 2 + (u >> 2);
            int gk = (u & 3) * 8;
            gload_lds16(src + (size_t)(base0 + row) * Kd + k0t + gk, dst + cbase * 8);
        }
    };

    f32x4 acc[8][4] = {};

    // prologue: tile0 all + tile1 kh0
    for (int s = 0; s < 6 && s < NS; ++s) stage(s);
    asm volatile("s_waitcnt vmcnt(8)" ::: "memory");
    __builtin_amdgcn_s_barrier();
    __builtin_amdgcn_sched_barrier(0);

    for (int t = 0; t < nt; ++t) {
        const int buf = t & 1;
#pragma unroll
        for (int q = 0; q < 4; ++q) {
            const int kh = q >> 1;
            const int ih = q & 1;
            bf16x8 af[4], bfv[4];
#pragma unroll
            for (int i = 0; i < 4; ++i) {
                int row = wr * 128 + (ih * 4 + i) * 16 + lr;
                int sr = row >> 1;
                int us = (((row & 1) * 4 + g)) ^ (sr & 7);
                af[i] = *(const bf16x8*)(Ab[buf][kh] + sr * 64 + us * 8);
            }
#pragma unroll
            for (int j = 0; j < 4; ++j) {
                int row = wc * 64 + j * 16 + lr;
                int sr = row >> 1;
                int us = (((row & 1) * 4 + g)) ^ (sr & 7);
                bfv[j] = *(const bf16x8*)(Bb[buf][kh] + sr * 64 + us * 8);
            }
            const int P = t * 4 + q;
            if (P + 6 < NS) stage(P + 6);
            if (q == 1) {
                if (t <= nt - 2) { asm volatile("s_waitcnt vmcnt(8)" ::: "memory"); }
                else             { asm volatile("s_waitcnt vmcnt(0)" ::: "memory"); }
            } else if (q == 3) {
                if (t <= nt - 3)      { asm volatile("s_waitcnt vmcnt(8)" ::: "memory"); }
                else if (t == nt - 2) { asm volatile("s_waitcnt vmcnt(4)" ::: "memory"); }
            }
            __builtin_amdgcn_s_barrier();
            __builtin_amdgcn_sched_barrier(0);
            __builtin_amdgcn_s_setprio(1);
#pragma unroll
            for (int i = 0; i < 4; ++i)
#pragma unroll
                for (int j = 0; j < 4; ++j)
                    acc[ih*4 + i][j] = __builtin_amdgcn_mfma_f32_16x16x32_bf16(
                        af[i], bfv[j], acc[ih*4 + i][j], 0, 0, 0);
            __builtin_amdgcn_s_setprio(0);
            __builtin_amdgcn_s_barrier();
            __builtin_amdgcn_sched_barrier(0);
        }
    }

#pragma unroll
    for (int i = 0; i < 8; ++i) {
#pragma unroll
        for (int j = 0; j < 4; ++j) {
            int col = n0 + wc*64 + j*16 + lr;
            float bv = 0.f;
            if (BIAS) bv = bias[col];
#pragma unroll
            for (int r = 0; r < 4; ++r) {
                int row = m0 + wr*128 + i*16 + g*4 + r;
                float v = acc[i][j][r] + bv;
                if (RELU) v = fmaxf(v, 0.f);
                Cout[(size_t)row * N + col] = __float2bfloat16(v);
            }
        }
    }
}

// ---------------------------------------------------------------------------
// Flash attention (unchanged from r13/r14).
// ---------------------------------------------------------------------------
__global__ void __launch_bounds__(256) attn_kernel(const bf16* __restrict__ qkv, bf16* __restrict__ o)
{
    const int bh = blockIdx.x;
    const int z  = blockIdx.y;
    const int b = bh >> 3, h = bh & 7;
    const int tid = threadIdx.x, lane = tid & 63, w = tid >> 6;
    const int g = lane >> 4, lr = lane & 15;
    const int qlo = z, qhi = 15 - z;
    const float SCL = 0.125f * 1.44269504089f;

    __shared__ short Ks[128][72];
    __shared__ short Vs[8192];

    const size_t base = (size_t)b * TSEQ * 1536;

    bf16x8 qfL[2], qfH[2];
#pragma unroll
    for (int kk = 0; kk < 2; ++kk) {
        qfL[kk] = *(const bf16x8*)(qkv + base + (size_t)(qlo*64 + w*16 + lr) * 1536 + h*64 + kk*32 + g*8);
        qfH[kk] = *(const bf16x8*)(qkv + base + (size_t)(qhi*64 + w*16 + lr) * 1536 + h*64 + kk*32 + g*8);
    }

    f32x4 accL[4] = {}, accH[4] = {};
    float mL = -1e30f, lL = 0.f, mH = -1e30f, lH = 0.f;

    const short* vtr = &Vs[lane * 4];

    auto proc = [&](const bf16x8* qf, f32x4* acc, float& m, float& l, int qt, int kt) {
        f32x4 st[8];
        __builtin_amdgcn_s_setprio(1);
#pragma unroll
        for (int j = 0; j < 8; ++j) {
            st[j] = f32x4{0.f, 0.f, 0.f, 0.f};
#pragma unroll
            for (int kk = 0; kk < 2; ++kk) {
                bf16x8 af = *(const bf16x8*)(&Ks[j*16 + lr][kk*32 + g*8]);
                st[j] = __builtin_amdgcn_mfma_f32_16x16x32_bf16(af, qf[kk], st[j], 0, 0, 0);
            }
        }
        __builtin_amdgcn_s_setprio(0);
        const int qg = qt*64 + w*16 + lr;
        const bool diag = (kt == (qt >> 1));
        float vmax = -1e30f;
#pragma unroll
        for (int j = 0; j < 8; ++j)
#pragma unroll
            for (int r = 0; r < 4; ++r) {
                float v = st[j][r] * SCL;
                if (diag && (kt*128 + j*16 + g*4 + r) > qg) v = -1e30f;
                st[j][r] = v;
                vmax = fmaxf(vmax, v);
            }
        vmax = fmaxf(vmax, __shfl_xor(vmax, 16));
        vmax = fmaxf(vmax, __shfl_xor(vmax, 32));
        if (!__all(vmax <= m + 8.f)) {
            float mn = fmaxf(m, vmax);
            float alpha = exp2f(m - mn);
            l *= alpha;
            float av[4];
#pragma unroll
            for (int r = 0; r < 4; ++r) av[r] = __shfl(alpha, g*4 + r);
#pragma unroll
            for (int dj = 0; dj < 4; ++dj)
#pragma unroll
                for (int r = 0; r < 4; ++r) acc[dj][r] *= av[r];
            m = mn;
        }
        float psum = 0.f;
        bf16x4 pf[8];
#pragma unroll
        for (int j = 0; j < 8; ++j)
#pragma unroll
            for (int r = 0; r < 4; ++r) {
                float p = exp2f(st[j][r] - m);
                psum += p;
                pf[j][r] = f2bf_bits(p);
            }
        psum += __shfl_xor(psum, 16);
        psum += __shfl_xor(psum, 32);
        l += psum;
#pragma unroll
        for (int half = 0; half < 4; ++half) {
            bf16x4 vf[2][4];
#pragma unroll
            for (int jj = 0; jj < 2; ++jj)
#pragma unroll
                for (int dj = 0; dj < 4; ++dj) {
                    asm volatile("ds_read_b64_tr_b16 %0, %1"
                        : "=v"(vf[jj][dj])
                        : "v"((const __attribute__((address_space(3))) short*)
                              (vtr + ((half*2 + jj)*4 + dj) * 256)));
                }
            asm volatile("s_waitcnt lgkmcnt(0)" ::: "memory");
            __builtin_amdgcn_sched_barrier(0);
            __builtin_amdgcn_s_setprio(1);
#pragma unroll
            for (int jj = 0; jj < 2; ++jj)
#pragma unroll
                for (int dj = 0; dj < 4; ++dj)
                    acc[dj] = MFMA16K16(pf[half*2 + jj], vf[jj][dj], acc[dj]);
            __builtin_amdgcn_s_setprio(0);
        }
    };

    const int ktmax = qhi >> 1;
    for (int kt = 0; kt <= ktmax; ++kt) {
#pragma unroll
        for (int it = 0; it < 4; ++it) {
            int idx = tid + it * 256;
            int row = idx >> 3;
            int col = (idx & 7) << 3;
            *(bf16x8*)(&Ks[row][col]) =
                *(const bf16x8*)(qkv + base + (size_t)(kt*128 + row)*1536 + 512 + h*64 + col);
            bf16x8 vv = *(const bf16x8*)(qkv + base + (size_t)(kt*128 + row)*1536 + 1024 + h*64 + col);
            int dst = ((row >> 4)*4 + (col >> 4))*256 + (row & 15)*16 + (col & 8);
            *(bf16x8*)(&Vs[dst]) = vv;
        }
        __syncthreads();
        proc(qfH, accH, mH, lH, qhi, kt);
        if (kt <= (qlo >> 1)) proc(qfL, accL, mL, lL, qlo, kt);
        __syncthreads();
    }

    auto wout = [&](const f32x4* acc, float l, int qt) {
        float linv = 1.f / l;
        float lv[4];
#pragma unroll
        for (int r = 0; r < 4; ++r) lv[r] = __shfl(linv, g*4 + r);
#pragma unroll
        for (int dj = 0; dj < 4; ++dj)
#pragma unroll
            for (int r = 0; r < 4; ++r) {
                int trow = qt*64 + w*16 + g*4 + r;
                o[((size_t)(b*TSEQ + trow))*512 + h*64 + dj*16 + lr] =
                    __float2bfloat16(acc[dj][r] * lv[r]);
            }
    };
    wout(accH, lH, qhi);
    wout(accL, lL, qlo);
}

// ---------------------------------------------------------------------------
// Fused residual + LayerNorm (r14 version).
// ---------------------------------------------------------------------------
template<bool HAS_RES>
__global__ void __launch_bounds__(256) ln_kernel(
    const bf16* __restrict__ y_, const bf16* __restrict__ xin,
    bf16* __restrict__ xb,
    const float* __restrict__ gamma, const float* __restrict__ beta)
{
    int row = blockIdx.x * 4 + (threadIdx.x >> 6);
    int lane = threadIdx.x & 63;
    int c0 = lane * 8;
    size_t rb = (size_t)row * CDIM + c0;
    float u[8];
    bf16x8 yv = *(const bf16x8*)(y_ + rb);
#pragma unroll
    for (int i = 0; i < 8; ++i) u[i] = bf2f(yv[i]);
    if (HAS_RES) {
        bf16x8 xv = *(const bf16x8*)(xin + rb);
#pragma unroll
        for (int i = 0; i < 8; ++i) u[i] += bf2f(xv[i]);
    }
    float s = 0.f, sq = 0.f;
#pragma unroll
    for (int i = 0; i < 8; ++i) { s += u[i]; sq += u[i]*u[i]; }
#pragma unroll
    for (int off = 1; off < 64; off <<= 1) { s += __shfl_xor(s, off); sq += __shfl_xor(sq, off); }
    float mean = s * (1.f / 512.f);
    float var  = sq * (1.f / 512.f) - mean * mean;
    float rstd = rsqrtf(var + 1e-5f);
    float4 g0 = *(const float4*)(gamma + c0);
    float4 g1 = *(const float4*)(gamma + c0 + 4);
    float4 be0 = *(const float4*)(beta + c0);
    float4 be1v = *(const float4*)(beta + c0 + 4);
    float gv[8] = {g0.x,g0.y,g0.z,g0.w,g1.x,g1.y,g1.z,g1.w};
    float bv[8] = {be0.x,be0.y,be0.z,be0.w,be1v.x,be1v.y,be1v.z,be1v.w};
    bf16x8 ob;
#pragma unroll
    for (int i = 0; i < 8; ++i)
        ob[i] = f2bf_bits((u[i] - mean) * rstd * gv[i] + bv[i]);
    *(bf16x8*)(xb + rb) = ob;
}

// ---------------------------------------------------------------------------
// Embedding glue
// ---------------------------------------------------------------------------
__global__ void __launch_bounds__(256) obs_convert(const float* __restrict__ obs, bf16* __restrict__ out)
{
    int idx = (blockIdx.x * 256 + threadIdx.x) * 4;
    float4 v = *(const float4*)(obs + idx);
    bf16x4 o = { f2bf_bits(v.x), f2bf_bits(v.y), f2bf_bits(v.z), f2bf_bits(v.w) };
    *(bf16x4*)(out + idx) = o;
}

__global__ void __launch_bounds__(256) concat_kernel(
    const bf16* __restrict__ obs_emb, const int* __restrict__ action,
    const float* __restrict__ E_act, bf16* __restrict__ cc)
{
    int row = blockIdx.x;
    int a = action[row];
    int c = threadIdx.x * 4;
    if (c < 512) {
        *(bf16x4*)(cc + (size_t)row * 1024 + c) =
            *(const bf16x4*)(obs_emb + (size_t)row * 512 + c);
    } else {
        float4 v = *(const float4*)(E_act + (size_t)a * 512 + (c - 512));
        bf16x4 o = { f2bf_bits(v.x), f2bf_bits(v.y), f2bf_bits(v.z), f2bf_bits(v.w) };
        *(bf16x4*)(cc + (size_t)row * 1024 + c) = o;
    }
}

// ---------------------------------------------------------------------------
extern "C" void kernel_launch(void* const* d_in, const int* in_sizes, int n_in,
                              void* d_out, int out_size, void* d_ws, size_t ws_size,
                              hipStream_t stream)
{
    const float* obs    = (const float*)d_in[0];
    const int*   action = (const int*)  d_in[1];
    const int*   step   = (const int*)  d_in[2];
    const float* W_obs  = (const float*)d_in[3];
    const float* b_obs  = (const float*)d_in[4];
    const float* E_act  = (const float*)d_in[5];
    const float* W_traj = (const float*)d_in[6];
    const float* b_traj = (const float*)d_in[7];
    const float* E_time = (const float*)d_in[8];
    const float* Wq  = (const float*)d_in[9];
    const float* Wk  = (const float*)d_in[10];
    const float* Wv  = (const float*)d_in[11];
    const float* Wp  = (const float*)d_in[12];
    const float* bp  = (const float*)d_in[13];
    const float* W1  = (const float*)d_in[14];
    const float* b1  = (const float*)d_in[15];
    const float* W2  = (const float*)d_in[16];
    const float* b2  = (const float*)d_in[17];
    const float* g1  = (const float*)d_in[18];
    const float* be1 = (const float*)d_in[19];
    const float* g2  = (const float*)d_in[20];
    const float* be2 = (const float*)d_in[21];
    const float* gf  = (const float*)d_in[22];
    const float* bfp = (const float*)d_in[23];
    const float* W_oh = (const float*)d_in[24];
    const float* b_oh = (const float*)d_in[25];
    const float* W_rh = (const float*)d_in[26];
    const float* b_rh = (const float*)d_in[27];
    const float* W_dh = (const float*)d_in[28];
    const float* b_dh = (const float*)d_in[29];

    char* ws  = (char*)d_ws;
    bf16* wsb = (bf16*)ws;

    long off = 0;
    const long oWT_obs  = off; off += 512L * 128;
    const long oWT_traj = off; off += 512L * 1024;
    const long oWT_qkv  = off; off += 6L * 1536 * 512;
    const long oWT_p    = off; off += 6L * 512 * 512;
    const long oWT_1    = off; off += 6L * 2048 * 512;
    const long oWT_2    = off; off += 6L * 512 * 2048;
    const long oWT_hd   = off; off += 256L * 512;
    size_t byteOff = ((size_t)off * 2 + 255) & ~(size_t)255;

    auto take = [&](size_t bytes) {
        void* p = ws + byteOff;
        byteOff = (byteOff + bytes + 255) & ~(size_t)255;
        return p;
    };
    float* head_bias = (float*)take(256 * 4);
    bf16*  xb   = (bf16*) take((size_t)MROWS * 512 * 2);
    bf16*  qkv  = (bf16*) take((size_t)MROWS * 1536 * 2);
    bf16*  o    = (bf16*) take((size_t)MROWS * 512 * 2);
    bf16*  hbuf = (bf16*) take((size_t)MROWS * 2048 * 2);
    (void)ws_size; (void)in_sizes; (void)n_in; (void)out_size;

    PrepArgs pa;
    int nj = 0;
    auto addJob = [&](const float* src, long dstOff, int nrows, int kd, int type) {
        pa.jobs[nj].src = src; pa.jobs[nj].dstOff = dstOff;
        pa.jobs[nj].nrows = nrows; pa.jobs[nj].kd = kd; pa.jobs[nj].type = type; ++nj;
    };
    addJob(W_obs,  oWT_obs,  512, 128,  0);
    addJob(W_traj, oWT_traj, 512, 1024, 0);
    for (int l = 0; l < 6; ++l) {
        long qb = oWT_qkv + (long)l * 1536 * 512;
        addJob(Wq + (long)l * 8 * 512 * 64, qb,               512, 512, 1);
        addJob(Wk + (long)l * 8 * 512 * 64, qb + 512L * 512,  512, 512, 1);
        addJob(Wv + (long)l * 8 * 512 * 64, qb + 1024L * 512, 512, 512, 1);
        addJob(Wp + (long)l * 512 * 512,  oWT_p + (long)l * 512 * 512,  512,  512,  0);
        addJob(W1 + (long)l * 512 * 2048, oWT_1 + (long)l * 2048 * 512, 2048, 512,  0);
        addJob(W2 + (long)l * 2048 * 512, oWT_2 + (long)l * 512 * 2048, 512,  2048, 0);
    }
    addJob(W_oh, oWT_hd,             128, 512, 0);
    addJob(W_rh, oWT_hd + 128L*512,  41,  512, 0);
    addJob(W_dh, oWT_hd + 169L*512,  1,   512, 0);
    addJob(nullptr, oWT_hd + 170L*512, 86, 512, 3);

    prep_weights<<<dim3(256, nj), 256, 0, stream>>>(pa, wsb);
    build_head_bias<<<1, 256, 0, stream>>>(b_oh, b_rh, b_dh, head_bias);

    // ---- embedding ----
    bf16* obs_bf = o;
    obs_convert<<<(MROWS * 128) / 1024, 256, 0, stream>>>(obs, obs_bf);
    bf16* obs_emb = qkv;
    gemm_kernel<64, 128, 1, true, false><<<dim3(64, 8), 256, 0, stream>>>(
        obs_bf, wsb + oWT_obs, obs_emb, b_obs, MROWS, 512, 128, nullptr, nullptr);
    bf16* cc = hbuf;
    concat_kernel<<<MROWS, 256, 0, stream>>>(obs_emb, action, E_act, cc);
    gemm_kernel<64, 128, 4, true, false><<<dim3(64, 8), 256, 0, stream>>>(
        cc, wsb + oWT_traj, xb, b_traj, MROWS, 512, 1024, step, E_time);

    // ---- layers ----
    for (int l = 0; l < 6; ++l) {
        gemm_kernel<128, 64, 1, false, false><<<dim3(64, 12), 256, 0, stream>>>(
            xb, wsb + oWT_qkv + (long)l * 1536 * 512, qkv, nullptr, MROWS, 1536, 512, nullptr, nullptr);
        attn_kernel<<<dim3(64, 8), 256, 0, stream>>>(qkv, o);
        gemm_kernel<64, 128, 1, true, false><<<dim3(64, 8), 256, 0, stream>>>(
            o, wsb + oWT_p + (long)l * 512 * 512, hbuf, bp + (long)l * 512, MROWS, 512, 512, nullptr, nullptr);
        ln_kernel<true><<<MROWS / 4, 256, 0, stream>>>(
            hbuf, xb, xb, g1 + l * 512, be1 + l * 512);
        gemm8p_kernel<true, true><<<dim3(32, 8), 512, 0, stream>>>(
            xb, wsb + oWT_1 + (long)l * 2048 * 512, hbuf, b1 + l * 2048, MROWS, 2048, 512);
        gemm_kernel<64, 128, 1, true, false><<<dim3(64, 8), 256, 0, stream>>>(
            hbuf, wsb + oWT_2 + (long)l * 512 * 2048, o, b2 + l * 512, MROWS, 512, 2048, nullptr, nullptr);
        ln_kernel<true><<<MROWS / 4, 256, 0, stream>>>(
            o, xb, xb, g2 + l * 512, be2 + l * 512);
    }

    // ---- final norm (in-place on xb) + heads ----
    ln_kernel<false><<<MROWS / 4, 256, 0, stream>>>(
        xb, nullptr, xb, gf, bfp);
    gemm_kernel<64, 128, 2, true, false><<<dim3(64, 4), 256, 0, stream>>>(
        xb, wsb + oWT_hd, d_out, head_bias, MROWS, 256, 512, nullptr, nullptr);
}